// Round 8
// baseline (789.691 us; speedup 1.0000x reference)
//
#include <hip/hip_runtime.h>

#define N_NODES 50000
#define N_EDGES 800000

#define SCAN_CHUNK 256
#define SCAN_BLOCKS ((N_NODES + SCAN_CHUNK - 1) / SCAN_CHUNK) // 196

static inline size_t alignUp(size_t x, size_t a) { return (x + a - 1) & ~(a - 1); }

// clang ext-vector float4 (scalar-element vector type accepted by
// __builtin_nontemporal_*; HIP's float4 is a class and is rejected — R7).
typedef float fx4 __attribute__((ext_vector_type(4)));

// ---------------- CSR build ----------------

__global__ void k_zero_i32(int* __restrict__ p, int n) {
    int i = blockIdx.x * 256 + threadIdx.x;
    if (i < n) p[i] = 0;
}

// count degrees; first 128 threads also zero the csr_col over-read pad
__global__ void k_count(const int* __restrict__ row, int* __restrict__ count,
                        int* __restrict__ pad) {
    int e = blockIdx.x * 256 + threadIdx.x;
    if (e < 128) pad[e] = 0;
    if (e < N_EDGES) atomicAdd(&count[row[e]], 1);
}

__global__ void k_blocksum(const int* __restrict__ count, int* __restrict__ bsum) {
    __shared__ int s[256];
    int t = threadIdx.x;
    int i = blockIdx.x * 256 + t;
    int v = (i < N_NODES) ? count[i] : 0;
    s[t] = v;
    __syncthreads();
    for (int off = 128; off > 0; off >>= 1) {
        if (t < off) s[t] += s[t + off];
        __syncthreads();
    }
    if (t == 0) bsum[blockIdx.x] = s[0];
}

__global__ void k_scan_bsum(int* __restrict__ bsum) {
    __shared__ int s[256];
    int t = threadIdx.x;
    int v = (t < SCAN_BLOCKS) ? bsum[t] : 0;
    s[t] = v;
    __syncthreads();
    for (int off = 1; off < 256; off <<= 1) {
        int add = (t >= off) ? s[t - off] : 0;
        __syncthreads();
        s[t] += add;
        __syncthreads();
    }
    if (t < SCAN_BLOCKS) bsum[t] = s[t] - v; // exclusive
}

__global__ void k_scan_final(const int* __restrict__ count, const int* __restrict__ bsum,
                             int* __restrict__ offsets, int* __restrict__ cursor,
                             float* __restrict__ dinv) {
    __shared__ int s[256];
    int t = threadIdx.x;
    int i = blockIdx.x * 256 + t;
    int v = (i < N_NODES) ? count[i] : 0;
    s[t] = v;
    __syncthreads();
    for (int off = 1; off < 256; off <<= 1) {
        int add = (t >= off) ? s[t - off] : 0;
        __syncthreads();
        s[t] += add;
        __syncthreads();
    }
    if (i < N_NODES) {
        int excl = s[t] - v + bsum[blockIdx.x];
        offsets[i] = excl;
        cursor[i]  = excl;
        dinv[i]    = rsqrtf((float)(v + 1)); // +1 self-loop; always > 0
    }
}

__global__ void k_scatter(const int* __restrict__ row, const int* __restrict__ col,
                          int* __restrict__ cursor, int* __restrict__ csr_col) {
    int e = blockIdx.x * 256 + threadIdx.x;
    if (e < N_EDGES) {
        int r = row[e];
        int pos = atomicAdd(&cursor[r], 1);
        csr_col[pos] = col[e];
    }
}

// ---------------- prescale: o[i,:] = dinv[i] * f[i,:]  (F=64, float4 grain) ----

__global__ void k_prescale64(const float* __restrict__ f, const float* __restrict__ dinv,
                             float* __restrict__ o) {
    int i = blockIdx.x * 256 + threadIdx.x; // float4 index
    if (i < N_NODES * 16) {
        int node = i >> 4;
        float d = dinv[node];
        float4 v = reinterpret_cast<const float4*>(f)[i];
        reinterpret_cast<float4*>(o)[i] = make_float4(v.x * d, v.y * d, v.z * d, v.w * d);
    }
}

// ---------------- XCD-pinned column-panel aggregation ----------------
// out[i, cols(p)] = dinv_i * ( h'[i] + sum_c h'[c] )[cols(p)] (+bias)
// Panel = 16 columns (3.2 MB footprint < 4 MB per-XCD L2). Panel p is pinned
// to XCD(s) via the empirical blockIdx%8 -> XCD round-robin: every gather an
// XCD issues targets its own resident panel, so the L3 refetch (R5: 210 MB =
// 8 XCDs x full matrix) collapses to one panel fill per XCD.
// Lane layout: g = lane>>2 (16 edge slots), cc = lane&3 (float4 within panel).
// One batch = 8 loads x 16 edges = 128 edges, predicated accumulate (pad=128).
// csr loads + output stores are nontemporal so streams don't evict the panel.

template <int F, bool BIAS>
__global__ __launch_bounds__(256) void k_aggp(const float* __restrict__ hs, float* __restrict__ out,
        const int* __restrict__ csr_col, const int* __restrict__ offsets,
        const int* __restrict__ count, const float* __restrict__ dinv,
        const float* __restrict__ bias) {
    constexpr int NP = F / 16;       // panels: 8 (F=128) or 4 (F=64)
    constexpr int SH = (F == 128) ? 9 : 8; // row stride shift (bytes)
    int sub = blockIdx.x & 7;
    int p, node;
    if constexpr (NP == 8) {
        p = sub;
        node = (blockIdx.x >> 3) * 4 + (threadIdx.x >> 6);
    } else {
        p = sub >> 1;
        node = (blockIdx.x >> 3) * 8 + (sub & 1) * 4 + (threadIdx.x >> 6);
    }
    int lane = threadIdx.x & 63;
    int g = lane >> 2;   // edge slot within a load (16 rows per instruction)
    int cc = lane & 3;   // float4 chunk within the 16-col panel
    uint32_t fo = (uint32_t)(p * 64 + cc * 16); // byte offset within row
    const char* base = (const char*)hs;

    int n = __builtin_amdgcn_readfirstlane(count[node]);
    int start = __builtin_amdgcn_readfirstlane(offsets[node]);
    const int* cp = csr_col + start;

    fx4 acc = {0.f, 0.f, 0.f, 0.f};

    for (int e = 0; e < n; e += 128) {
        int c[8];
#pragma unroll
        for (int u = 0; u < 8; u++)
            c[u] = __builtin_nontemporal_load(&cp[e + 16 * u + g]); // pad(128) makes over-read safe
        fx4 v[8];
#pragma unroll
        for (int u = 0; u < 8; u++)
            v[u] = *reinterpret_cast<const fx4*>(base + (((uint32_t)c[u] << SH) + fo));
#pragma unroll
        for (int u = 0; u < 8; u++) {
            if (e + 16 * u + g < n) acc += v[u];
        }
    }

    // reduce across the 16 edge slots (strides 4,8,16,32)
#pragma unroll
    for (int s = 4; s < 64; s <<= 1) {
        acc.x += __shfl_xor(acc.x, s);
        acc.y += __shfl_xor(acc.y, s);
        acc.z += __shfl_xor(acc.z, s);
        acc.w += __shfl_xor(acc.w, s);
    }

    if (lane < 4) {
        fx4 self = *reinterpret_cast<const fx4*>(base + (((uint32_t)node << SH) + fo));
        float d = dinv[node];
        fx4 o = (acc + self) * d;
        if (BIAS) {
            fx4 bv = *reinterpret_cast<const fx4*>(&bias[p * 16 + cc * 4]);
            o += bv;
        }
        __builtin_nontemporal_store(o,
            reinterpret_cast<fx4*>((char*)out + (((uint32_t)node << SH) + fo)));
    }
}

// ---------------- fp32 GEMM (R4 known-good: BK=32, BN=64) ----------------
// out[r,c] = post( x[r,:] @ W[:,c] ), post = (+bias) -> relu -> (*dinv[r])
// __launch_bounds__(256,4) caps VGPR at 128 (R3 spilled at 256 VGPR);
// '#pragma unroll 1' on the K-tile loop prevents whole-kernel flattening.
// All RPT-dependent branches are `if constexpr` (R6 compile failure: plain
// if instantiated xr[4..7] on float[4] -> -Warray-bounds hard error).

template <int K, int NOUT, int BM, bool RELU, bool BIAS, bool SCALE>
__global__ __launch_bounds__(256, 4) void k_gemm(const float* __restrict__ x,
        const float* __restrict__ W, const float* __restrict__ bias,
        const float* __restrict__ dinv, float* __restrict__ out, int nrows) {
    constexpr int BK = 32, BN = 64;
    constexpr int NCB = NOUT / BN;  // column blocks per row
    constexpr int RPT = BM / 16;    // rows per thread (8 or 4)
    __shared__ float xt[BK * BM];
    __shared__ float wt[BK * BN];

    int tid = threadIdx.x;
    int rg = tid & 15;  // row group
    int cg = tid >> 4;  // col group: cols cg*4..+3 of the 64-col strip
    int row0 = (blockIdx.x / NCB) * BM;
    int col0 = (blockIdx.x % NCB) * BN;

    float acc[RPT][4] = {};

#pragma unroll 1
    for (int kk = 0; kk < K; kk += BK) {
        __syncthreads();
        // ---- x tile: BM rows x 32 k, coalesced float4, swizzled transpose store
#pragma unroll
        for (int t = 0; t < BM / 32; ++t) {
            int idx = tid + t * 256;
            int r = idx >> 3;
            int kc = (idx & 7) * 4;
            float4 v = make_float4(0.f, 0.f, 0.f, 0.f);
            int gr = row0 + r;
            if (gr < nrows) v = *reinterpret_cast<const float4*>(&x[(size_t)gr * K + kk + kc]);
            int rc = r ^ kc; // kc in {0..28}: swizzle within 32-row stripe
            xt[(kc + 0) * BM + rc] = v.x;
            xt[(kc + 1) * BM + rc] = v.y;
            xt[(kc + 2) * BM + rc] = v.z;
            xt[(kc + 3) * BM + rc] = v.w;
        }
        // ---- W tile: 32 k x 64 n
#pragma unroll
        for (int t = 0; t < 2; ++t) {
            int idx = tid + t * 256;
            int k = idx >> 4;
            int c = (idx & 15) * 4;
            *reinterpret_cast<float4*>(&wt[k * BN + c]) =
                *reinterpret_cast<const float4*>(&W[(size_t)(kk + k) * NOUT + col0 + c]);
        }
        __syncthreads();

#pragma unroll
        for (int k = 0; k < BK; ++k) {
            int s = k & 28;
            float4 wv = *reinterpret_cast<const float4*>(&wt[k * BN + cg * 4]);
            float wr[4] = {wv.x, wv.y, wv.z, wv.w};
            float xr[RPT];
            float4 x0 = *reinterpret_cast<const float4*>(&xt[k * BM + ((rg * 4) ^ s)]);
            xr[0] = x0.x; xr[1] = x0.y; xr[2] = x0.z; xr[3] = x0.w;
            if constexpr (RPT == 8) {
                float4 x1 = *reinterpret_cast<const float4*>(&xt[k * BM + (((rg * 4) ^ s) + 64)]);
                xr[4] = x1.x; xr[5] = x1.y; xr[6] = x1.z; xr[7] = x1.w;
            }
#pragma unroll
            for (int a = 0; a < RPT; a++)
#pragma unroll
                for (int b = 0; b < 4; b++) acc[a][b] += xr[a] * wr[b];
        }
    }

    float bv[4];
    if (BIAS) {
#pragma unroll
        for (int b = 0; b < 4; b++) bv[b] = bias[col0 + cg * 4 + b];
    }
#pragma unroll
    for (int a = 0; a < RPT; a++) {
        int r = rg * 4 + (a & 3) + ((a >= 4) ? 64 : 0);
        int gr = row0 + r;
        if (gr >= nrows) continue;
        float d = SCALE ? dinv[gr] : 1.f;
        float o[4];
#pragma unroll
        for (int b = 0; b < 4; b++) {
            float v = acc[a][b];
            if (BIAS) v += bv[b];
            if (RELU) v = fmaxf(v, 0.f);
            o[b] = v * d;
        }
        *reinterpret_cast<float4*>(&out[(size_t)gr * NOUT + col0 + cg * 4]) =
            make_float4(o[0], o[1], o[2], o[3]);
    }
}

// ---------------- launch ----------------

extern "C" void kernel_launch(void* const* d_in, const int* in_sizes, int n_in,
                              void* d_out, int out_size, void* d_ws, size_t ws_size,
                              hipStream_t stream) {
    const float* feat = (const float*)d_in[0]; // [N, 64]
    const float* W1 = (const float*)d_in[1];   // [64, 128]
    const float* b1 = (const float*)d_in[2];
    const float* W2 = (const float*)d_in[3];   // [128, 128]
    const float* b2 = (const float*)d_in[4];
    const float* W3 = (const float*)d_in[5];   // [128, 64]
    const float* b3 = (const float*)d_in[6];
    const int* ei = (const int*)d_in[7];       // [2, E]
    const int* row = ei;
    const int* col = ei + N_EDGES;
    float* out = (float*)d_out;

    // workspace bump allocator (256B aligned)
    char* ws = (char*)d_ws;
    size_t off = 0;
    auto alloc = [&](size_t bytes) {
        void* p = ws + off;
        off = alignUp(off + bytes, 256);
        return p;
    };
    float* B0      = (float*)alloc((size_t)N_NODES * 128 * 4);
    float* B1      = (float*)alloc((size_t)N_NODES * 128 * 4);
    float* dinv    = (float*)alloc((size_t)N_NODES * 4);
    int*   count   = (int*)alloc((size_t)N_NODES * 4);
    int*   offsets = (int*)alloc((size_t)N_NODES * 4);
    int*   cursor  = (int*)alloc((size_t)N_NODES * 4);
    int*   bsum    = (int*)alloc(1024);
    int*   csr_col = (int*)alloc((size_t)(N_EDGES + 128) * 4); // +128 pad for over-read
    // featS (N x 64) overlays B1: dead before GEMM1 writes B1.
    float* featS   = B1;

    const int eb = (N_EDGES + 255) / 256;
    const int rb128 = (N_NODES + 127) / 128; // 391
    const int rb64  = (N_NODES + 63) / 64;   // 782
    const int aggp128_grid = (N_NODES / 4) * 8; // 100000 (node-quad x 8 panels)
    const int aggp64_grid  = (N_NODES / 8) * 8; // 50000  (node-octet x {half,panel})

    // CSR build (every call — no cached state allowed)
    k_zero_i32<<<(N_NODES + 255) / 256, 256, 0, stream>>>(count, N_NODES);
    k_count<<<eb, 256, 0, stream>>>(row, count, csr_col + N_EDGES);
    k_blocksum<<<SCAN_BLOCKS, 256, 0, stream>>>(count, bsum);
    k_scan_bsum<<<1, 256, 0, stream>>>(bsum);
    k_scan_final<<<SCAN_BLOCKS, 256, 0, stream>>>(count, bsum, offsets, cursor, dinv);
    k_scatter<<<eb, 256, 0, stream>>>(row, col, cursor, csr_col);

    // features pre-scaled by dinv (so aggregate gathers need no dinv[c])
    k_prescale64<<<(N_NODES * 16 + 255) / 256, 256, 0, stream>>>(feat, dinv, featS);

    // Layer 1: agg1 = A_hat@feat (F=64), then x1' = dinv .* relu(agg1@W1+b1)
    k_aggp<64, false><<<aggp64_grid, 256, 0, stream>>>(featS, B0, csr_col, offsets, count, dinv, nullptr);
    k_gemm<64, 128, 128, true, true, true><<<rb128 * 2, 256, 0, stream>>>(B0, W1, b1, dinv, B1, N_NODES);

    // Layer 2: agg2 = A_hat@x1 (F=128), then x2 = relu(agg2@W2+b2) (unscaled)
    k_aggp<128, false><<<aggp128_grid, 256, 0, stream>>>(B1, B0, csr_col, offsets, count, dinv, nullptr);
    k_gemm<128, 128, 128, true, true, false><<<rb128 * 2, 256, 0, stream>>>(B0, W2, b2, dinv, B1, N_NODES);

    // Layer 3: h3' = dinv .* (x2@W3), then out = A_hat-agg + b3
    k_gemm<128, 64, 64, false, false, true><<<rb64, 256, 0, stream>>>(B1, W3, nullptr, dinv, B0, N_NODES);
    k_aggp<64, true><<<aggp64_grid, 256, 0, stream>>>(B0, out, csr_col, offsets, count, dinv, b3);
}

// Round 10
// 344.282 us; speedup vs baseline: 2.2937x; 2.2937x over previous
//
#include <hip/hip_runtime.h>

#define N_NODES 50000
#define N_EDGES 800000

#define SCAN_CHUNK 256
#define SCAN_BLOCKS ((N_NODES + SCAN_CHUNK - 1) / SCAN_CHUNK) // 196

static inline size_t alignUp(size_t x, size_t a) { return (x + a - 1) & ~(a - 1); }

// ---------------- CSR build ----------------

__global__ void k_zero_i32(int* __restrict__ p, int n) {
    int i = blockIdx.x * 256 + threadIdx.x;
    if (i < n) p[i] = 0;
}

// count degrees; first 128 threads also zero the csr_col over-read pad
__global__ void k_count(const int* __restrict__ row, int* __restrict__ count,
                        int* __restrict__ pad) {
    int e = blockIdx.x * 256 + threadIdx.x;
    if (e < 128) pad[e] = 0;
    if (e < N_EDGES) atomicAdd(&count[row[e]], 1);
}

__global__ void k_blocksum(const int* __restrict__ count, int* __restrict__ bsum) {
    __shared__ int s[256];
    int t = threadIdx.x;
    int i = blockIdx.x * 256 + t;
    int v = (i < N_NODES) ? count[i] : 0;
    s[t] = v;
    __syncthreads();
    for (int off = 128; off > 0; off >>= 1) {
        if (t < off) s[t] += s[t + off];
        __syncthreads();
    }
    if (t == 0) bsum[blockIdx.x] = s[0];
}

__global__ void k_scan_bsum(int* __restrict__ bsum) {
    __shared__ int s[256];
    int t = threadIdx.x;
    int v = (t < SCAN_BLOCKS) ? bsum[t] : 0;
    s[t] = v;
    __syncthreads();
    for (int off = 1; off < 256; off <<= 1) {
        int add = (t >= off) ? s[t - off] : 0;
        __syncthreads();
        s[t] += add;
        __syncthreads();
    }
    if (t < SCAN_BLOCKS) bsum[t] = s[t] - v; // exclusive
}

__global__ void k_scan_final(const int* __restrict__ count, const int* __restrict__ bsum,
                             int* __restrict__ offsets, int* __restrict__ cursor,
                             float* __restrict__ dinv) {
    __shared__ int s[256];
    int t = threadIdx.x;
    int i = blockIdx.x * 256 + t;
    int v = (i < N_NODES) ? count[i] : 0;
    s[t] = v;
    __syncthreads();
    for (int off = 1; off < 256; off <<= 1) {
        int add = (t >= off) ? s[t - off] : 0;
        __syncthreads();
        s[t] += add;
        __syncthreads();
    }
    if (i < N_NODES) {
        int excl = s[t] - v + bsum[blockIdx.x];
        offsets[i] = excl;
        cursor[i]  = excl;
        dinv[i]    = rsqrtf((float)(v + 1)); // +1 self-loop; always > 0
    }
}

__global__ void k_scatter(const int* __restrict__ row, const int* __restrict__ col,
                          int* __restrict__ cursor, int* __restrict__ csr_col) {
    int e = blockIdx.x * 256 + threadIdx.x;
    if (e < N_EDGES) {
        int r = row[e];
        int pos = atomicAdd(&cursor[r], 1);
        csr_col[pos] = col[e];
    }
}

// ---------------- prescale: o[i,:] = dinv[i] * f[i,:]  (F=64, float4 grain) ----

__global__ void k_prescale64(const float* __restrict__ f, const float* __restrict__ dinv,
                             float* __restrict__ o) {
    int i = blockIdx.x * 256 + threadIdx.x; // float4 index
    if (i < N_NODES * 16) {
        int node = i >> 4;
        float d = dinv[node];
        float4 v = reinterpret_cast<const float4*>(f)[i];
        reinterpret_cast<float4*>(o)[i] = make_float4(v.x * d, v.y * d, v.z * d, v.w * d);
    }
}

// ---------------- R4-proven F=64 aggregation (wave per node, float2 lanes) ----
// out[i] = dinv_i * ( h'[i] + sum_c h'[c] ) (+bias), h' = dinv .* h

template <bool BIAS>
__global__ __launch_bounds__(256) void k_agg64(const float* __restrict__ hs, float* __restrict__ out,
        const int* __restrict__ csr_col, const int* __restrict__ offsets,
        const int* __restrict__ count, const float* __restrict__ dinv,
        const float* __restrict__ bias) {
    int lane = threadIdx.x & 63;
    int node = blockIdx.x * 4 + (threadIdx.x >> 6);
    int half = lane >> 5;
    int f2 = lane & 31;
    const float2* h2 = reinterpret_cast<const float2*>(hs);

    float ax[8], ay[8];
#pragma unroll
    for (int u = 0; u < 8; u++) { ax[u] = 0.f; ay[u] = 0.f; }

    int n = count[node];
    const int* cp = csr_col + offsets[node];

    int e = 0;
    for (; e + 16 <= n; e += 16) {
        int c[8];
#pragma unroll
        for (int u = 0; u < 8; u++) c[u] = cp[e + 2 * u + half];
#pragma unroll
        for (int u = 0; u < 8; u++) {
            float2 v = h2[(size_t)c[u] * 32 + f2];
            ax[u] += v.x; ay[u] += v.y;
        }
    }
    if (e < n) { // one predicated batch covers rem 1..15
#pragma unroll
        for (int u = 0; u < 8; u++) {
            int eid = e + 2 * u + half;
            int c = cp[eid]; // padded, safe
            float2 v = h2[(size_t)c * 32 + f2];
            if (eid < n) { ax[u] += v.x; ay[u] += v.y; }
        }
    }

    float sx = 0.f, sy = 0.f;
#pragma unroll
    for (int u = 0; u < 8; u++) { sx += ax[u]; sy += ay[u]; }
    sx += __shfl_xor(sx, 32);
    sy += __shfl_xor(sy, 32);
    if (half == 0) {
        float2 self = h2[(size_t)node * 32 + f2];
        float d = dinv[node];
        float ox = (sx + self.x) * d, oy = (sy + self.y) * d;
        if (BIAS) { ox += bias[2 * f2]; oy += bias[2 * f2 + 1]; }
        reinterpret_cast<float2*>(out)[(size_t)node * 32 + f2] = make_float2(ox, oy);
    }
}

// ---------------- Layer-2 (F=128) XCD-panel aggregation, CHUNKED mapping ----
// Panel = 16 cols (3.2 MB < 4 MB per-XCD L2). Tests the CHUNKED hypothesis:
// panel = blockIdx / CPP (contiguous blockIdx range per panel); R8 falsified
// the blockIdx&7 round-robin pin. ONE gather instruction = 16 edges x 4
// chunks = 64 lanes. Each wave handles 4 nodes; block (4 waves) covers 16
// nodes -> CPP = ceil(N/16) = 3125 (R9 bug: 782 left 3/4 of nodes unwritten).
// Write is per (node,panel), disjoint across blocks: mapping is perf-only.

__global__ __launch_bounds__(256) void k_aggp2(const float* __restrict__ hs,
        float* __restrict__ out, const int* __restrict__ csr_col,
        const int* __restrict__ offsets, const int* __restrict__ count,
        const float* __restrict__ dinv) {
    constexpr int CPP = 3125; // blocks per panel: 3125*16 = 50000 nodes exactly
    int panel = blockIdx.x / CPP;
    int chunk = blockIdx.x % CPP;
    int lane = threadIdx.x & 63;
    int node0 = chunk * 16 + (threadIdx.x >> 6) * 4; // this wave's 4 nodes
    int cc = lane & 3;
    int es = lane >> 2; // edge slot 0..15
    uint32_t fo = (uint32_t)(panel * 64 + cc * 16);  // byte offset within 512B row
    const char* base = (const char*)hs;

    int myn = node0 + (lane >> 4); // node this lane reports for (k = lane>>4)
    bool vn = myn < N_NODES;
    int n_l = vn ? count[myn] : 0;
    int off_l = vn ? offsets[myn] : 0;
    const int* cp_l = csr_col + off_l;

    int n0 = __shfl(n_l, 0), n1 = __shfl(n_l, 16);
    int n2 = __shfl(n_l, 32), n3 = __shfl(n_l, 48);
    int maxn = max(max(n0, n1), max(n2, n3));

    float4 a0 = make_float4(0.f, 0.f, 0.f, 0.f);
    float4 a1 = a0, a2 = a0, a3 = a0;

    for (int e = 0; e < maxn; e += 16) {
        // one instruction: 4 nodes x 16 csr entries (pad(128) covers tail)
        int c_all = cp_l[e + (lane & 15)];
        int c0 = __shfl(c_all, es);
        int c1 = __shfl(c_all, 16 + es);
        int c2 = __shfl(c_all, 32 + es);
        int c3 = __shfl(c_all, 48 + es);
        // one gather instruction per node: 16 edges x 4 chunks = 64 lanes
        float4 v0 = *reinterpret_cast<const float4*>(base + (((uint32_t)c0 << 9) + fo));
        float4 v1 = *reinterpret_cast<const float4*>(base + (((uint32_t)c1 << 9) + fo));
        float4 v2 = *reinterpret_cast<const float4*>(base + (((uint32_t)c2 << 9) + fo));
        float4 v3 = *reinterpret_cast<const float4*>(base + (((uint32_t)c3 << 9) + fo));
        int ei = e + es;
        if (ei < n0) { a0.x += v0.x; a0.y += v0.y; a0.z += v0.z; a0.w += v0.w; }
        if (ei < n1) { a1.x += v1.x; a1.y += v1.y; a1.z += v1.z; a1.w += v1.w; }
        if (ei < n2) { a2.x += v2.x; a2.y += v2.y; a2.z += v2.z; a2.w += v2.w; }
        if (ei < n3) { a3.x += v3.x; a3.y += v3.y; a3.z += v3.z; a3.w += v3.w; }
    }

    // reduce over the 16 edge slots (lane bits 2..5), keep cc distinct
#pragma unroll
    for (int s = 4; s < 64; s <<= 1) {
        a0.x += __shfl_xor(a0.x, s); a0.y += __shfl_xor(a0.y, s);
        a0.z += __shfl_xor(a0.z, s); a0.w += __shfl_xor(a0.w, s);
        a1.x += __shfl_xor(a1.x, s); a1.y += __shfl_xor(a1.y, s);
        a1.z += __shfl_xor(a1.z, s); a1.w += __shfl_xor(a1.w, s);
        a2.x += __shfl_xor(a2.x, s); a2.y += __shfl_xor(a2.y, s);
        a2.z += __shfl_xor(a2.z, s); a2.w += __shfl_xor(a2.w, s);
        a3.x += __shfl_xor(a3.x, s); a3.y += __shfl_xor(a3.y, s);
        a3.z += __shfl_xor(a3.z, s); a3.w += __shfl_xor(a3.w, s);
    }

    // lanes l = k*16 + cc (i.e. (l>>2)&3 == 0) write node k's chunk cc
    if (((lane >> 2) & 3) == 0 && vn) {
        int k = lane >> 4;
        float4 tot = (k == 0) ? a0 : ((k == 1) ? a1 : ((k == 2) ? a2 : a3));
        float4 self = *reinterpret_cast<const float4*>(base + (((uint32_t)myn << 9) + fo));
        float d = dinv[myn];
        *reinterpret_cast<float4*>((char*)out + (((uint32_t)myn << 9) + fo)) =
            make_float4((tot.x + self.x) * d, (tot.y + self.y) * d,
                        (tot.z + self.z) * d, (tot.w + self.w) * d);
    }
}

// ---------------- fp32 GEMM (R4 known-good: BK=32, BN=64) ----------------
// out[r,c] = post( x[r,:] @ W[:,c] ), post = (+bias) -> relu -> (*dinv[r])
// __launch_bounds__(256,4) caps VGPR at 128 (R3 spilled at 256 VGPR);
// '#pragma unroll 1' on the K-tile loop prevents whole-kernel flattening.
// RPT-dependent branches are `if constexpr` (R6 compile failure).

template <int K, int NOUT, int BM, bool RELU, bool BIAS, bool SCALE>
__global__ __launch_bounds__(256, 4) void k_gemm(const float* __restrict__ x,
        const float* __restrict__ W, const float* __restrict__ bias,
        const float* __restrict__ dinv, float* __restrict__ out, int nrows) {
    constexpr int BK = 32, BN = 64;
    constexpr int NCB = NOUT / BN;  // column blocks per row
    constexpr int RPT = BM / 16;    // rows per thread (8 or 4)
    __shared__ float xt[BK * BM];
    __shared__ float wt[BK * BN];

    int tid = threadIdx.x;
    int rg = tid & 15;  // row group
    int cg = tid >> 4;  // col group: cols cg*4..+3 of the 64-col strip
    int row0 = (blockIdx.x / NCB) * BM;
    int col0 = (blockIdx.x % NCB) * BN;

    float acc[RPT][4] = {};

#pragma unroll 1
    for (int kk = 0; kk < K; kk += BK) {
        __syncthreads();
        // ---- x tile: BM rows x 32 k, coalesced float4, swizzled transpose store
#pragma unroll
        for (int t = 0; t < BM / 32; ++t) {
            int idx = tid + t * 256;
            int r = idx >> 3;
            int kc = (idx & 7) * 4;
            float4 v = make_float4(0.f, 0.f, 0.f, 0.f);
            int gr = row0 + r;
            if (gr < nrows) v = *reinterpret_cast<const float4*>(&x[(size_t)gr * K + kk + kc]);
            int rc = r ^ kc; // kc in {0..28}: swizzle within 32-row stripe
            xt[(kc + 0) * BM + rc] = v.x;
            xt[(kc + 1) * BM + rc] = v.y;
            xt[(kc + 2) * BM + rc] = v.z;
            xt[(kc + 3) * BM + rc] = v.w;
        }
        // ---- W tile: 32 k x 64 n
#pragma unroll
        for (int t = 0; t < 2; ++t) {
            int idx = tid + t * 256;
            int k = idx >> 4;
            int c = (idx & 15) * 4;
            *reinterpret_cast<float4*>(&wt[k * BN + c]) =
                *reinterpret_cast<const float4*>(&W[(size_t)(kk + k) * NOUT + col0 + c]);
        }
        __syncthreads();

#pragma unroll
        for (int k = 0; k < BK; ++k) {
            int s = k & 28;
            float4 wv = *reinterpret_cast<const float4*>(&wt[k * BN + cg * 4]);
            float wr[4] = {wv.x, wv.y, wv.z, wv.w};
            float xr[RPT];
            float4 x0 = *reinterpret_cast<const float4*>(&xt[k * BM + ((rg * 4) ^ s)]);
            xr[0] = x0.x; xr[1] = x0.y; xr[2] = x0.z; xr[3] = x0.w;
            if constexpr (RPT == 8) {
                float4 x1 = *reinterpret_cast<const float4*>(&xt[k * BM + (((rg * 4) ^ s) + 64)]);
                xr[4] = x1.x; xr[5] = x1.y; xr[6] = x1.z; xr[7] = x1.w;
            }
#pragma unroll
            for (int a = 0; a < RPT; a++)
#pragma unroll
                for (int b = 0; b < 4; b++) acc[a][b] += xr[a] * wr[b];
        }
    }

    float bv[4];
    if (BIAS) {
#pragma unroll
        for (int b = 0; b < 4; b++) bv[b] = bias[col0 + cg * 4 + b];
    }
#pragma unroll
    for (int a = 0; a < RPT; a++) {
        int r = rg * 4 + (a & 3) + ((a >= 4) ? 64 : 0);
        int gr = row0 + r;
        if (gr >= nrows) continue;
        float d = SCALE ? dinv[gr] : 1.f;
        float o[4];
#pragma unroll
        for (int b = 0; b < 4; b++) {
            float v = acc[a][b];
            if (BIAS) v += bv[b];
            if (RELU) v = fmaxf(v, 0.f);
            o[b] = v * d;
        }
        *reinterpret_cast<float4*>(&out[(size_t)gr * NOUT + col0 + cg * 4]) =
            make_float4(o[0], o[1], o[2], o[3]);
    }
}

// ---------------- launch ----------------

extern "C" void kernel_launch(void* const* d_in, const int* in_sizes, int n_in,
                              void* d_out, int out_size, void* d_ws, size_t ws_size,
                              hipStream_t stream) {
    const float* feat = (const float*)d_in[0]; // [N, 64]
    const float* W1 = (const float*)d_in[1];   // [64, 128]
    const float* b1 = (const float*)d_in[2];
    const float* W2 = (const float*)d_in[3];   // [128, 128]
    const float* b2 = (const float*)d_in[4];
    const float* W3 = (const float*)d_in[5];   // [128, 64]
    const float* b3 = (const float*)d_in[6];
    const int* ei = (const int*)d_in[7];       // [2, E]
    const int* row = ei;
    const int* col = ei + N_EDGES;
    float* out = (float*)d_out;

    // workspace bump allocator (256B aligned)
    char* ws = (char*)d_ws;
    size_t off = 0;
    auto alloc = [&](size_t bytes) {
        void* p = ws + off;
        off = alignUp(off + bytes, 256);
        return p;
    };
    float* B0      = (float*)alloc((size_t)N_NODES * 128 * 4);
    float* B1      = (float*)alloc((size_t)N_NODES * 128 * 4);
    float* dinv    = (float*)alloc((size_t)N_NODES * 4);
    int*   count   = (int*)alloc((size_t)N_NODES * 4);
    int*   offsets = (int*)alloc((size_t)N_NODES * 4);
    int*   cursor  = (int*)alloc((size_t)N_NODES * 4);
    int*   bsum    = (int*)alloc(1024);
    int*   csr_col = (int*)alloc((size_t)(N_EDGES + 128) * 4); // +128 pad for over-read
    // featS (N x 64) overlays B1: dead before GEMM1 writes B1.
    float* featS   = B1;

    const int eb = (N_EDGES + 255) / 256;
    const int rb128 = (N_NODES + 127) / 128; // 391
    const int rb64  = (N_NODES + 63) / 64;   // 782
    const int agg_grid = N_NODES / 4;        // 12500 (one node per wave)
    const int aggp2_grid = 8 * 3125;         // 25000 (8 panels x 3125 chunks)

    // CSR build (every call — no cached state allowed)
    k_zero_i32<<<(N_NODES + 255) / 256, 256, 0, stream>>>(count, N_NODES);
    k_count<<<eb, 256, 0, stream>>>(row, count, csr_col + N_EDGES);
    k_blocksum<<<SCAN_BLOCKS, 256, 0, stream>>>(count, bsum);
    k_scan_bsum<<<1, 256, 0, stream>>>(bsum);
    k_scan_final<<<SCAN_BLOCKS, 256, 0, stream>>>(count, bsum, offsets, cursor, dinv);
    k_scatter<<<eb, 256, 0, stream>>>(row, col, cursor, csr_col);

    // features pre-scaled by dinv (so aggregate gathers need no dinv[c])
    k_prescale64<<<(N_NODES * 16 + 255) / 256, 256, 0, stream>>>(feat, dinv, featS);

    // Layer 1: agg1 = A_hat@feat (F=64), then x1' = dinv .* relu(agg1@W1+b1)
    k_agg64<false><<<agg_grid, 256, 0, stream>>>(featS, B0, csr_col, offsets, count, dinv, nullptr);
    k_gemm<64, 128, 128, true, true, true><<<rb128 * 2, 256, 0, stream>>>(B0, W1, b1, dinv, B1, N_NODES);

    // Layer 2: agg2 = A_hat@x1 (F=128, panel kernel), then x2 = relu(agg2@W2+b2)
    k_aggp2<<<aggp2_grid, 256, 0, stream>>>(B1, B0, csr_col, offsets, count, dinv);
    k_gemm<128, 128, 128, true, true, false><<<rb128 * 2, 256, 0, stream>>>(B0, W2, b2, dinv, B1, N_NODES);

    // Layer 3: h3' = dinv .* (x2@W3), then out = A_hat-agg + b3
    k_gemm<128, 64, 64, false, false, true><<<rb64, 256, 0, stream>>>(B1, W3, nullptr, dinv, B0, N_NODES);
    k_agg64<true><<<agg_grid, 256, 0, stream>>>(B0, out, csr_col, offsets, count, dinv, b3);
}